// Round 3
// baseline (209.974 us; speedup 1.0000x reference)
//
#include <hip/hip_runtime.h>

#define NN 50000
#define DD 128
#define NB 196          // ceil(50000/256)

typedef __attribute__((ext_vector_type(8))) short bf16x8;
typedef __attribute__((ext_vector_type(4))) float f32x4;

static __device__ __forceinline__ unsigned short f2bf(float x) {
    unsigned int u = __float_as_uint(x);
    unsigned int r = (u + 0x7fffu + ((u >> 16) & 1u)) >> 16;
    return (unsigned short)r;
}

// ---------- x -> bf16 (block 0 also builds Wt: W[k][j] f32 -> Wt[j][k] bf16) ----------
__global__ void __launch_bounds__(256) convert_kernel(
    const float* __restrict__ x, const float* __restrict__ W,
    unsigned short* __restrict__ xb, unsigned short* __restrict__ Wt)
{
    int tid = threadIdx.x;
    if (blockIdx.x == 0) {
        for (int idx = tid; idx < DD * DD; idx += 256) {
            int k = idx >> 7;
            int j = idx & 127;
            Wt[j * DD + k] = f2bf(W[idx]);
        }
    }
    int i = blockIdx.x * 256 + tid;
    int stride = gridDim.x * 256;
    const int total = NN * DD / 4;
    for (; i < total; i += stride) {
        float4 v = reinterpret_cast<const float4*>(x)[i];
        ushort4 o;
        o.x = f2bf(v.x); o.y = f2bf(v.y); o.z = f2bf(v.z); o.w = f2bf(v.w);
        reinterpret_cast<ushort4*>(xb)[i] = o;
    }
}

// ---------- CSR build ----------
__global__ void __launch_bounds__(256) hist_kernel(
    const int* __restrict__ row, int* __restrict__ counts, int E)
{
    int i = blockIdx.x * 256 + threadIdx.x;
    int stride = gridDim.x * 256;
    for (int e = i; e < E; e += stride) atomicAdd(&counts[row[e]], 1);
}

__global__ void __launch_bounds__(256) scan_local_kernel(
    const int* __restrict__ counts, int* __restrict__ wptr, int* __restrict__ bsum)
{
    __shared__ int s[256];
    int tid = threadIdx.x;
    int i = blockIdx.x * 256 + tid;
    int v = (i < NN) ? counts[i] : 0;
    s[tid] = v;
    __syncthreads();
    #pragma unroll
    for (int d = 1; d < 256; d <<= 1) {
        int t = (tid >= d) ? s[tid - d] : 0;
        __syncthreads();
        s[tid] += t;
        __syncthreads();
    }
    if (i < NN) wptr[i] = s[tid] - v;
    if (tid == 255) bsum[blockIdx.x] = s[255];
}

__global__ void __launch_bounds__(256) scan_bsum_kernel(int* __restrict__ bsum)
{
    __shared__ int s[256];
    int tid = threadIdx.x;
    int v = (tid < NB) ? bsum[tid] : 0;
    s[tid] = v;
    __syncthreads();
    #pragma unroll
    for (int d = 1; d < 256; d <<= 1) {
        int t = (tid >= d) ? s[tid - d] : 0;
        __syncthreads();
        s[tid] += t;
        __syncthreads();
    }
    if (tid < NB) bsum[tid] = s[tid] - v;
}

__global__ void __launch_bounds__(256) scan_add_kernel(
    int* __restrict__ wptr, const int* __restrict__ bsum)
{
    int i = blockIdx.x * 256 + threadIdx.x;
    if (i < NN) wptr[i] += bsum[blockIdx.x];
}

// after this, wptr[r] == segment end (start = end - counts[r])
__global__ void __launch_bounds__(256) edge_scatter_kernel(
    const int* __restrict__ row, const int* __restrict__ col,
    int* __restrict__ wptr, unsigned short* __restrict__ edge_col, int E)
{
    int i = blockIdx.x * 256 + threadIdx.x;
    int stride = gridDim.x * 256;
    for (int e = i; e < E; e += stride) {
        int r = row[e];
        int pos = atomicAdd(&wptr[r], 1);
        edge_col[pos] = (unsigned short)col[e];
    }
}

// ---------- fused gather(mean) + Linear bf16 MFMA + bias + ReLU ----------
// 64 nodes/block: 8 groups x 32 lanes, 8 nodes per group.
__global__ void __launch_bounds__(256) fused_kernel(
    const unsigned short* __restrict__ xb,
    const int* __restrict__ wptr, const int* __restrict__ counts,
    const unsigned short* __restrict__ edge_col,
    const unsigned short* __restrict__ Wt,
    const float* __restrict__ bias,
    float* __restrict__ out)
{
    __shared__ unsigned short w_lds[DD * DD];   // 32KB [j][k]
    __shared__ unsigned short a_lds[64 * DD];   // 16KB [local_row][k]
    __shared__ float b_lds[DD];

    const int tid = threadIdx.x;
    const int i0 = blockIdx.x * 64;

    {
        const uint4* src = reinterpret_cast<const uint4*>(Wt);
        uint4* dst = reinterpret_cast<uint4*>(w_lds);
        #pragma unroll
        for (int it = 0; it < 8; ++it) dst[tid + it * 256] = src[tid + it * 256];
    }
    if (tid < DD) b_lds[tid] = bias[tid];

    const int grp = tid >> 5;
    const int lane = tid & 31;

    // gather 8 nodes per group; lane i owns cols [4i, 4i+4)
    #pragma unroll
    for (int r8 = 0; r8 < 8; ++r8) {
        int lr = grp * 8 + r8;
        int node = i0 + lr;
        float4 acc = make_float4(0.f, 0.f, 0.f, 0.f);
        float inv = 1.f;
        if (node < NN) {
            int cnt = counts[node];
            int end = wptr[node];
            int start = end - cnt;
            for (int base = start; base < end; base += 32) {
                int m = min(32, end - base);
                int cl = (base + lane < end) ? (int)edge_col[base + lane] : 0;
                #pragma unroll 2
                for (int ii = 0; ii < m; ++ii) {
                    int c = __shfl(cl, ii, 32);
                    uint2 u = reinterpret_cast<const uint2*>(xb + (size_t)c * DD)[lane];
                    acc.x += __uint_as_float(u.x << 16);
                    acc.y += __uint_as_float(u.x & 0xffff0000u);
                    acc.z += __uint_as_float(u.y << 16);
                    acc.w += __uint_as_float(u.y & 0xffff0000u);
                }
            }
            inv = 1.0f / fmaxf((float)cnt, 1.0f);
        }
        ushort4 o;
        o.x = f2bf(acc.x * inv); o.y = f2bf(acc.y * inv);
        o.z = f2bf(acc.z * inv); o.w = f2bf(acc.w * inv);
        reinterpret_cast<ushort4*>(&a_lds[lr * DD])[lane] = o;
    }
    __syncthreads();

    const int wave = tid >> 6;
    const int l64 = tid & 63;
    const int lrow = l64 & 15;
    const int kgrp = l64 >> 4;

    bf16x8 afrag[4];
    #pragma unroll
    for (int s = 0; s < 4; ++s) {
        const unsigned short* p = &a_lds[(wave * 16 + lrow) * DD + s * 32 + kgrp * 8];
        afrag[s] = *reinterpret_cast<const bf16x8*>(p);
    }

    f32x4 acc[8];
    #pragma unroll
    for (int t = 0; t < 8; ++t) acc[t] = (f32x4){0.f, 0.f, 0.f, 0.f};

    #pragma unroll
    for (int t = 0; t < 8; ++t) {
        #pragma unroll
        for (int s = 0; s < 4; ++s) {
            const unsigned short* p = &w_lds[(t * 16 + lrow) * DD + s * 32 + kgrp * 8];
            bf16x8 bfrag = *reinterpret_cast<const bf16x8*>(p);
            acc[t] = __builtin_amdgcn_mfma_f32_16x16x32_bf16(afrag[s], bfrag, acc[t], 0, 0, 0);
        }
    }

    // D layout: col = lane&15, row = (lane>>4)*4 + reg   [m89-verified]
    #pragma unroll
    for (int t = 0; t < 8; ++t) {
        int colj = t * 16 + lrow;
        float bb = b_lds[colj];
        #pragma unroll
        for (int r = 0; r < 4; ++r) {
            int grow = i0 + wave * 16 + kgrp * 4 + r;
            if (grow < NN) {
                out[(size_t)grow * DD + colj] = fmaxf(acc[t][r] + bb, 0.f);
            }
        }
    }
}

// ---------- fallback: atomic scatter + f32 gemm (if ws too small) ----------
__global__ void __launch_bounds__(256) scatter_atomic_kernel(
    const float* __restrict__ x,
    const int* __restrict__ row, const int* __restrict__ col,
    float* __restrict__ agg, int* __restrict__ counts, int E)
{
    int gid = blockIdx.x * blockDim.x + threadIdx.x;
    int group = gid >> 5;
    int lane = threadIdx.x & 31;
    int ngroups = (gridDim.x * blockDim.x) >> 5;
    for (int e = group; e < E; e += ngroups) {
        int r = row[e];
        int c = col[e];
        float4 v = reinterpret_cast<const float4*>(x + (size_t)c * DD)[lane];
        float* dst = agg + (size_t)r * DD + lane * 4;
        unsafeAtomicAdd(dst + 0, v.x);
        unsafeAtomicAdd(dst + 1, v.y);
        unsafeAtomicAdd(dst + 2, v.z);
        unsafeAtomicAdd(dst + 3, v.w);
        if (lane == 0) atomicAdd(counts + r, 1);
    }
}

__global__ void __launch_bounds__(256) wt_kernel(
    const float* __restrict__ W, unsigned short* __restrict__ Wt)
{
    for (int idx = threadIdx.x; idx < DD * DD; idx += 256) {
        int k = idx >> 7;
        int j = idx & 127;
        Wt[j * DD + k] = f2bf(W[idx]);
    }
}

__global__ void __launch_bounds__(256) gemm_kernel(
    const float* __restrict__ agg,
    const int* __restrict__ counts,
    const unsigned short* __restrict__ Wt,
    const float* __restrict__ bias,
    float* __restrict__ out)
{
    __shared__ unsigned short w_lds[DD * DD];
    __shared__ unsigned short a_lds[64 * DD];
    __shared__ float b_lds[DD];

    const int tid = threadIdx.x;
    const int i0 = blockIdx.x * 64;

    {
        const uint4* src = reinterpret_cast<const uint4*>(Wt);
        uint4* dst = reinterpret_cast<uint4*>(w_lds);
        #pragma unroll
        for (int it = 0; it < 8; ++it) dst[tid + it * 256] = src[tid + it * 256];
    }
    if (tid < DD) b_lds[tid] = bias[tid];

    #pragma unroll
    for (int it = 0; it < 8; ++it) {
        int idx = tid + it * 256;
        int r = idx >> 5;
        int c4 = idx & 31;
        int grow = i0 + r;
        float4 v = make_float4(0.f, 0.f, 0.f, 0.f);
        float inv = 0.f;
        if (grow < NN) {
            v = reinterpret_cast<const float4*>(agg + (size_t)grow * DD)[c4];
            inv = 1.0f / fmaxf((float)counts[grow], 1.0f);
        }
        ushort4 o;
        o.x = f2bf(v.x * inv); o.y = f2bf(v.y * inv);
        o.z = f2bf(v.z * inv); o.w = f2bf(v.w * inv);
        reinterpret_cast<ushort4*>(a_lds)[idx] = o;
    }
    __syncthreads();

    const int wave = tid >> 6;
    const int l64 = tid & 63;
    const int lrow = l64 & 15;
    const int kgrp = l64 >> 4;

    bf16x8 afrag[4];
    #pragma unroll
    for (int s = 0; s < 4; ++s) {
        const unsigned short* p = &a_lds[(wave * 16 + lrow) * DD + s * 32 + kgrp * 8];
        afrag[s] = *reinterpret_cast<const bf16x8*>(p);
    }

    f32x4 acc[8];
    #pragma unroll
    for (int t = 0; t < 8; ++t) acc[t] = (f32x4){0.f, 0.f, 0.f, 0.f};

    #pragma unroll
    for (int t = 0; t < 8; ++t) {
        #pragma unroll
        for (int s = 0; s < 4; ++s) {
            const unsigned short* p = &w_lds[(t * 16 + lrow) * DD + s * 32 + kgrp * 8];
            bf16x8 bfrag = *reinterpret_cast<const bf16x8*>(p);
            acc[t] = __builtin_amdgcn_mfma_f32_16x16x32_bf16(afrag[s], bfrag, acc[t], 0, 0, 0);
        }
    }

    #pragma unroll
    for (int t = 0; t < 8; ++t) {
        int colj = t * 16 + lrow;
        float bb = b_lds[colj];
        #pragma unroll
        for (int r = 0; r < 4; ++r) {
            int grow = i0 + wave * 16 + kgrp * 4 + r;
            if (grow < NN) {
                out[(size_t)grow * DD + colj] = fmaxf(acc[t][r] + bb, 0.f);
            }
        }
    }
}

extern "C" void kernel_launch(void* const* d_in, const int* in_sizes, int n_in,
                              void* d_out, int out_size, void* d_ws, size_t ws_size,
                              hipStream_t stream) {
    const float* x  = (const float*)d_in[0];
    const int* ei   = (const int*)d_in[1];
    const float* W  = (const float*)d_in[2];
    const float* b  = (const float*)d_in[3];
    float* out      = (float*)d_out;

    const int E = in_sizes[1] / 2;
    const int* row = ei;
    const int* col = ei + E;

    // ws layout (16B-aligned)
    char* wsc = (char*)d_ws;
    int* counts            = (int*)(wsc + 0);              // 200704 B
    int* wptr              = (int*)(wsc + 200704);         // 200704 B
    int* bsum              = (int*)(wsc + 401408);         // 1024 B
    unsigned short* edge_col = (unsigned short*)(wsc + 402432);   // 1280000 B
    unsigned short* Wt     = (unsigned short*)(wsc + 1682432);    // 32768 B
    unsigned short* xb     = (unsigned short*)(wsc + 1715200);    // 12800000 B
    const size_t WS_NEED = 14515200;

    if (ws_size >= WS_NEED) {
        hipMemsetAsync(counts, 0, (size_t)NN * sizeof(int), stream);
        convert_kernel<<<2048, 256, 0, stream>>>(x, W, xb, Wt);
        hist_kernel<<<2500, 256, 0, stream>>>(row, counts, E);
        scan_local_kernel<<<NB, 256, 0, stream>>>(counts, wptr, bsum);
        scan_bsum_kernel<<<1, 256, 0, stream>>>(bsum);
        scan_add_kernel<<<NB, 256, 0, stream>>>(wptr, bsum);
        edge_scatter_kernel<<<2500, 256, 0, stream>>>(row, col, wptr, edge_col, E);
        fused_kernel<<<(NN + 63) / 64, 256, 0, stream>>>(xb, wptr, counts, edge_col, Wt, b, out);
    } else {
        int* fc = (int*)d_ws;
        unsigned short* fWt = (unsigned short*)(wsc + 200704);
        hipMemsetAsync(d_out, 0, (size_t)NN * DD * sizeof(float), stream);
        hipMemsetAsync(fc, 0, (size_t)NN * sizeof(int), stream);
        wt_kernel<<<1, 256, 0, stream>>>(W, fWt);
        scatter_atomic_kernel<<<2048, 256, 0, stream>>>(x, row, col, out, fc, E);
        gemm_kernel<<<(NN + 63) / 64, 256, 0, stream>>>(out, fc, fWt, b, out);
    }
}